// Round 1
// baseline (221.171 us; speedup 1.0000x reference)
//
#include <hip/hip_runtime.h>

typedef __attribute__((ext_vector_type(8))) short bf16x8;
typedef __attribute__((ext_vector_type(4))) float f32x4;

#define NBLK  512
#define NTHR  256
#define BM    64
#define KTOT  256
#define NITER 16      // (524288/BM)/NBLK
#define DOUT  128

// short-index XOR swizzle: breaks the same-bank pattern of row-major [64][256]
// bf16 tiles read 16B/lane down a column (G4: stride-512B = 16-way conflict).
__device__ __forceinline__ int swz(int row, int k) {
  return (row * KTOT + k) ^ ((row & 7) << 3);
}

__device__ __forceinline__ unsigned short bf_rne(float x) {
  unsigned u = __builtin_bit_cast(unsigned, x);
  return (unsigned short)((u + 0x7FFFu + ((u >> 16) & 1u)) >> 16);
}

// split fp32 into bf16 hi (truncate) + bf16 lo (RNE of residual): x ~ hi+lo to 2^-15 rel
__device__ __forceinline__ void split2(float x, short& hi, short& lo) {
  unsigned u = __builtin_bit_cast(unsigned, x);
  float hf = __builtin_bit_cast(float, u & 0xFFFF0000u);
  hi = (short)(unsigned short)(u >> 16);
  lo = (short)bf_rne(x - hf);
}

__global__ __launch_bounds__(NTHR, 2)
void dagmm(const float* __restrict__ x0, const float* __restrict__ x1,
           const float* __restrict__ w0, const float* __restrict__ w1,
           const float* __restrict__ m0, const float* __restrict__ m1,
           float* __restrict__ out)
{
  __shared__ short lh[BM * KTOT];   // 32 KB  x-tile hi
  __shared__ short ll[BM * KTOT];   // 32 KB  x-tile lo

  const int t    = threadIdx.x;
  const int lane = t & 63;
  const int wv   = t >> 6;          // wave 0..3 -> owns output cols [wv*32, wv*32+32)
  const int l16  = lane & 15;
  const int lq   = lane >> 4;

  // ---------- per-wave weight fragments, resident in VGPRs for whole kernel ----------
  // B-frag layout (16x16x32): lane holds col = l16, k = lq*8 + j (j=0..7)
  bf16x8 bhi[2][8], blo[2][8];
#pragma unroll
  for (int c = 0; c < 2; ++c) {
    const int col = wv * 32 + c * 16 + l16;
#pragma unroll
    for (int ks = 0; ks < 8; ++ks) {
      const int k0 = ks * 32 + lq * 8;            // 0..248, never straddles 128
      const float* wp = (k0 < 128) ? (w0 + col * 128 + k0) : (w1 + col * 128 + (k0 - 128));
      const float* mp = (k0 < 128) ? (m0 + col * 128 + k0) : (m1 + col * 128 + (k0 - 128));
      float4 wa = *(const float4*)wp;
      float4 wb = *(const float4*)(wp + 4);
      float4 ma = *(const float4*)mp;
      float4 mb = *(const float4*)(mp + 4);
      float v[8] = {wa.x*ma.x, wa.y*ma.y, wa.z*ma.z, wa.w*ma.w,
                    wb.x*mb.x, wb.y*mb.y, wb.z*mb.z, wb.w*mb.w};
      bf16x8 hv, lv;
#pragma unroll
      for (int j = 0; j < 8; ++j) { short h, l; split2(v[j], h, l); hv[j] = h; lv[j] = l; }
      bhi[c][ks] = hv; blo[c][ks] = lv;
    }
  }

  const int T0 = blockIdx.x * NITER;

  // prefetch first half of tile 0
  float4 pre[8];
#pragma unroll
  for (int i = 0; i < 4; ++i) {
    const int c = t + NTHR * i;
    const int row = c >> 5, k8 = c & 31;
    const size_t g = (size_t)T0 * BM + row;
    const float* p = (k8 < 16) ? (x0 + g * 128 + k8 * 8) : (x1 + g * 128 + (k8 - 16) * 8);
    pre[2*i]   = *(const float4*)p;
    pre[2*i+1] = *(const float4*)(p + 4);
  }

  for (int it = 0; it < NITER; ++it) {
    const int T = T0 + it;

    // ---------- stage 64x256 x-tile into LDS as bf16 hi/lo (swizzled) ----------
#pragma unroll
    for (int i = 0; i < 8; ++i) {
      const int c = t + NTHR * i;
      const int row = c >> 5, k8 = c & 31;
      float4 a, b;
      if (i < 4) { a = pre[2*i]; b = pre[2*i+1]; }
      else {
        const size_t g = (size_t)T * BM + row;
        const float* p = (k8 < 16) ? (x0 + g * 128 + k8 * 8) : (x1 + g * 128 + (k8 - 16) * 8);
        a = *(const float4*)p; b = *(const float4*)(p + 4);
      }
      float v[8] = {a.x, a.y, a.z, a.w, b.x, b.y, b.z, b.w};
      bf16x8 hv, lv;
#pragma unroll
      for (int j = 0; j < 8; ++j) { short h, l; split2(v[j], h, l); hv[j] = h; lv[j] = l; }
      const int s = swz(row, k8 * 8);
      *(bf16x8*)&lh[s] = hv;
      *(bf16x8*)&ll[s] = lv;
    }
    __syncthreads();

    // issue first half of NEXT tile's loads now -> stay in flight under the MFMAs (T14)
    if (it + 1 < NITER) {
#pragma unroll
      for (int i = 0; i < 4; ++i) {
        const int c = t + NTHR * i;
        const int row = c >> 5, k8 = c & 31;
        const size_t g = (size_t)(T + 1) * BM + row;
        const float* p = (k8 < 16) ? (x0 + g * 128 + k8 * 8) : (x1 + g * 128 + (k8 - 16) * 8);
        pre[2*i]   = *(const float4*)p;
        pre[2*i+1] = *(const float4*)(p + 4);
      }
    }

    // ---------- MFMA: 4 row-tiles x 2 col-tiles, K=256, 3-term bf16 split ----------
    f32x4 acc[4][2];
#pragma unroll
    for (int rt = 0; rt < 4; ++rt)
#pragma unroll
      for (int c = 0; c < 2; ++c) acc[rt][c] = (f32x4){0.f, 0.f, 0.f, 0.f};

#pragma unroll
    for (int ks = 0; ks < 8; ++ks) {
      const int k0 = ks * 32 + lq * 8;
#pragma unroll
      for (int rt = 0; rt < 4; ++rt) {
        const int row = rt * 16 + l16;
        const int s = swz(row, k0);
        bf16x8 ah = *(const bf16x8*)&lh[s];
        bf16x8 al = *(const bf16x8*)&ll[s];
#pragma unroll
        for (int c = 0; c < 2; ++c) {
          acc[rt][c] = __builtin_amdgcn_mfma_f32_16x16x32_bf16(ah, bhi[c][ks], acc[rt][c], 0, 0, 0);
          acc[rt][c] = __builtin_amdgcn_mfma_f32_16x16x32_bf16(ah, blo[c][ks], acc[rt][c], 0, 0, 0);
          acc[rt][c] = __builtin_amdgcn_mfma_f32_16x16x32_bf16(al, bhi[c][ks], acc[rt][c], 0, 0, 0);
        }
      }
    }

    // ---------- store: C/D layout col=l16, row=lq*4+reg (m89-verified) ----------
#pragma unroll
    for (int rt = 0; rt < 4; ++rt)
#pragma unroll
      for (int c = 0; c < 2; ++c) {
        const int col = wv * 32 + c * 16 + l16;
        const size_t r0 = (size_t)T * BM + rt * 16 + lq * 4;
#pragma unroll
        for (int r = 0; r < 4; ++r)
          out[(r0 + r) * DOUT + col] = acc[rt][c][r];
      }
    __syncthreads();
  }
}

extern "C" void kernel_launch(void* const* d_in, const int* in_sizes, int n_in,
                              void* d_out, int out_size, void* d_ws, size_t ws_size,
                              hipStream_t stream) {
  const float* x0 = (const float*)d_in[0];
  const float* x1 = (const float*)d_in[1];
  const float* w0 = (const float*)d_in[2];
  const float* w1 = (const float*)d_in[3];
  const float* m0 = (const float*)d_in[4];
  const float* m1 = (const float*)d_in[5];
  dagmm<<<NBLK, NTHR, 0, stream>>>(x0, x1, w0, w1, m0, m1, (float*)d_out);
}

// Round 2
// 211.410 us; speedup vs baseline: 1.0462x; 1.0462x over previous
//
#include <hip/hip_runtime.h>

typedef __attribute__((ext_vector_type(8))) short bf16x8;
typedef __attribute__((ext_vector_type(4))) float f32x4;

#define NBLK  512
#define NTHR  512     // 8 waves
#define BM    32
#define KTOT  256
#define NITER 32      // 524288 / BM / NBLK
#define DOUT  128

// short-index XOR swizzle: kills same-bank pattern of row-major [32][256] bf16
// tile read 16B/lane down a column (16 rows -> 8 distinct 16B slots = 2-way = free)
__device__ __forceinline__ int swz(int row, int k) {
  return (row * KTOT + k) ^ ((row & 7) << 3);
}

__device__ __forceinline__ unsigned short bf_rne(float x) {
  unsigned u = __builtin_bit_cast(unsigned, x);
  return (unsigned short)((u + 0x7FFFu + ((u >> 16) & 1u)) >> 16);
}

// fp32 -> bf16 hi (truncate) + bf16 lo (RNE of residual); x ~ hi+lo to ~2^-15 rel
__device__ __forceinline__ void split2(float x, short& hi, short& lo) {
  unsigned u = __builtin_bit_cast(unsigned, x);
  float hf = __builtin_bit_cast(float, u & 0xFFFF0000u);
  hi = (short)(unsigned short)(u >> 16);
  lo = (short)bf_rne(x - hf);
}

__global__ __launch_bounds__(NTHR, 4)   // 4 waves/SIMD = 16 waves/CU -> VGPR <= 128
void dagmm(const float* __restrict__ x0, const float* __restrict__ x1,
           const float* __restrict__ w0, const float* __restrict__ w1,
           const float* __restrict__ m0, const float* __restrict__ m1,
           float* __restrict__ out)
{
  __shared__ short lh[BM * KTOT];   // 16 KB  x-tile hi
  __shared__ short ll[BM * KTOT];   // 16 KB  x-tile lo

  const int t    = threadIdx.x;
  const int lane = t & 63;
  const int w    = t >> 6;          // wave 0..7 -> owns output cols [w*16, w*16+16)
  const int l16  = lane & 15;
  const int lq   = lane >> 4;

  // ---------- per-wave weight fragments (16 cols), resident in VGPRs ----------
  // B-frag (16x16x32): lane holds col = l16, k = lq*8 + j
  bf16x8 bhi[8], blo[8];
  {
    const int col = w * 16 + l16;
#pragma unroll
    for (int ks = 0; ks < 8; ++ks) {
      const int k0 = ks * 32 + lq * 8;            // never straddles the 128 boundary
      const float* wp = (k0 < 128) ? (w0 + col * 128 + k0) : (w1 + col * 128 + (k0 - 128));
      const float* mp = (k0 < 128) ? (m0 + col * 128 + k0) : (m1 + col * 128 + (k0 - 128));
      float4 wa = *(const float4*)wp;
      float4 wb = *(const float4*)(wp + 4);
      float4 ma = *(const float4*)mp;
      float4 mb = *(const float4*)(mp + 4);
      float v[8] = {wa.x*ma.x, wa.y*ma.y, wa.z*ma.z, wa.w*ma.w,
                    wb.x*mb.x, wb.y*mb.y, wb.z*mb.z, wb.w*mb.w};
      bf16x8 hv, lv;
#pragma unroll
      for (int j = 0; j < 8; ++j) { short h, l; split2(v[j], h, l); hv[j] = h; lv[j] = l; }
      bhi[ks] = hv; blo[ks] = lv;
    }
  }

  // ---------- staging map: thread -> (row, 16 consecutive floats of K=256) ----------
  const int srow = t >> 4;            // 0..31
  const int sfo  = (t & 15) * 16;     // 0,16,...,240  (floats; <128 -> x0, else x1)
  const float* xb = (sfo < 128) ? (x0 + sfo) : (x1 + (sfo - 128));

  const int T0 = blockIdx.x * NITER;

  // prefetch tile 0 fully into regs (4x float4 = 64B/thread)
  float4 pre[4];
  {
    const float* p = xb + (size_t)(T0 * BM + srow) * 128;
#pragma unroll
    for (int i = 0; i < 4; ++i) pre[i] = *(const float4*)(p + 4 * i);
  }

  for (int it = 0; it < NITER; ++it) {
    const int T = T0 + it;

    // ---------- split prefetched tile -> LDS (hi/lo, swizzled) ----------
    {
      float v[16];
#pragma unroll
      for (int i = 0; i < 4; ++i) {
        v[4*i+0] = pre[i].x; v[4*i+1] = pre[i].y; v[4*i+2] = pre[i].z; v[4*i+3] = pre[i].w;
      }
#pragma unroll
      for (int half = 0; half < 2; ++half) {
        bf16x8 hv, lv;
#pragma unroll
        for (int j = 0; j < 8; ++j) { short h, l; split2(v[half*8+j], h, l); hv[j] = h; lv[j] = l; }
        const int s = swz(srow, sfo + half * 8);
        *(bf16x8*)&lh[s] = hv;
        *(bf16x8*)&ll[s] = lv;
      }
    }

    // issue NEXT tile's loads now -> in flight across barrier + MFMA phase
    if (it + 1 < NITER) {
      const float* p = xb + (size_t)((T + 1) * BM + srow) * 128;
#pragma unroll
      for (int i = 0; i < 4; ++i) pre[i] = *(const float4*)(p + 4 * i);
    }
    __syncthreads();

    // ---------- MFMA: 2 row-tiles x 1 col-tile, K=256, 3-term bf16 split ----------
    f32x4 acc[2];
    acc[0] = (f32x4){0.f, 0.f, 0.f, 0.f};
    acc[1] = (f32x4){0.f, 0.f, 0.f, 0.f};

#pragma unroll
    for (int ks = 0; ks < 8; ++ks) {
      const int k0 = ks * 32 + lq * 8;
#pragma unroll
      for (int rt = 0; rt < 2; ++rt) {
        const int s = swz(rt * 16 + l16, k0);
        bf16x8 ah = *(const bf16x8*)&lh[s];
        bf16x8 al = *(const bf16x8*)&ll[s];
        acc[rt] = __builtin_amdgcn_mfma_f32_16x16x32_bf16(ah, bhi[ks], acc[rt], 0, 0, 0);
        acc[rt] = __builtin_amdgcn_mfma_f32_16x16x32_bf16(ah, blo[ks], acc[rt], 0, 0, 0);
        acc[rt] = __builtin_amdgcn_mfma_f32_16x16x32_bf16(al, bhi[ks], acc[rt], 0, 0, 0);
      }
    }

    // ---------- store: C/D layout col=l16, row=lq*4+reg ----------
#pragma unroll
    for (int rt = 0; rt < 2; ++rt) {
      const int col = w * 16 + l16;
      const size_t r0 = (size_t)T * BM + rt * 16 + lq * 4;
#pragma unroll
      for (int r = 0; r < 4; ++r)
        out[(r0 + r) * DOUT + col] = acc[rt][r];
    }
    __syncthreads();
  }
}

extern "C" void kernel_launch(void* const* d_in, const int* in_sizes, int n_in,
                              void* d_out, int out_size, void* d_ws, size_t ws_size,
                              hipStream_t stream) {
  const float* x0 = (const float*)d_in[0];
  const float* x1 = (const float*)d_in[1];
  const float* w0 = (const float*)d_in[2];
  const float* w1 = (const float*)d_in[3];
  const float* m0 = (const float*)d_in[4];
  const float* m1 = (const float*)d_in[5];
  dagmm<<<NBLK, NTHR, 0, stream>>>(x0, x1, w0, w1, m0, m1, (float*)d_out);
}